// Round 2
// baseline (327.818 us; speedup 1.0000x reference)
//
#include <hip/hip_runtime.h>

typedef unsigned short u16;
typedef unsigned int u32;
typedef __bf16 bf16x8 __attribute__((ext_vector_type(8)));
typedef float f32x4 __attribute__((ext_vector_type(4)));
typedef u16 u16x8 __attribute__((ext_vector_type(8)));

#define T_SEQ 2048
#define DMODEL 2048
#define NQKV 6144
#define HD 128
#define NH 16
#define MROWS 4096

__device__ __forceinline__ u16 f2b(float f) {
  union { float f; u32 u; } a; a.f = f;
  u32 r = a.u + 0x7fffu + ((a.u >> 16) & 1u);
  return (u16)(r >> 16);
}
__device__ __forceinline__ float b2f(u16 h) {
  union { u32 u; float f; } a; a.u = ((u32)h) << 16;
  return a.f;
}
__device__ __forceinline__ void g2l16(const u16* g, u16* l) {
  __builtin_amdgcn_global_load_lds((const __attribute__((address_space(1))) u32*)g,
                                   (__attribute__((address_space(3))) u32*)l, 16, 0, 0);
}

#define BAR() do { asm volatile("" ::: "memory"); __builtin_amdgcn_s_barrier(); asm volatile("" ::: "memory"); } while (0)

__global__ void k_f32_to_bf16(const float* __restrict__ in, u16* __restrict__ out, int n) {
  int i = (blockIdx.x * 256 + threadIdx.x) * 8;
  if (i >= n) return;
  float4 a = *(const float4*)(in + i);
  float4 b = *(const float4*)(in + i + 4);
  u16x8 v;
  v[0] = f2b(a.x); v[1] = f2b(a.y); v[2] = f2b(a.z); v[3] = f2b(a.w);
  v[4] = f2b(b.x); v[5] = f2b(b.y); v[6] = f2b(b.z); v[7] = f2b(b.w);
  *(u16x8*)(out + i) = v;
}

// out[c][r] = bf16(in[r][c]); in is R x C f32
__global__ void k_transpose_bf16(const float* __restrict__ in, u16* __restrict__ out,
                                 int R, int C) {
  __shared__ u16 tile[32][33];
  const int c0 = blockIdx.x * 32, r0 = blockIdx.y * 32;
  const int tx = threadIdx.x & 31, ty = threadIdx.x >> 5;
#pragma unroll
  for (int i = 0; i < 32; i += 8)
    tile[ty + i][tx] = f2b(in[(size_t)(r0 + ty + i) * C + c0 + tx]);
  __syncthreads();
#pragma unroll
  for (int i = 0; i < 32; i += 8)
    out[(size_t)(c0 + ty + i) * R + r0 + tx] = tile[tx][ty + i];
}

__global__ void k_rope_cache(float* __restrict__ cosb, float* __restrict__ sinb) {
  int idx = blockIdx.x * 256 + threadIdx.x;
  int t = idx >> 6, d = idx & 63;
  float inv = powf(10000.0f, -(float)d * (1.0f / 64.0f));
  float fr = (float)t * inv;
  cosb[idx] = cosf(fr);
  sinb[idx] = sinf(fr);
}

// ---------------------------------------------------------------------------
// 8-phase deep-pipelined GEMM: C[M][N] = A[M][K] * B[N][K]^T, bf16 in, BK=64.
// Tile 256 x BN, 8 waves (wm in {0,1}, wn in {0..3}); per-wave output is
// NON-contiguous: 64 rows in each A-half x (BN/8) cols in each B-half, so the
// 4 phases per K-tile consume half-tiles in staggered order:
//   ph0:(A0,B0) ph1:(A1,B0) ph2:(A1,B1) ph3:(A0,B1)
// Staging (1 half-tile per phase, uniform stream order):
//   ph0: B1(t+1)->lB[buf^1][1]   ph1: A0(t+1)->lA[buf^1][0]
//   ph2: B0(t+2)->lB[buf  ][0]   ph3: A1(t+2)->lA[buf  ][1]
// Each target slot's last ds_read finished >=1 phase earlier (race-free).
// One counted vmcnt(LB+2) per K-tile at ph3 guarantees the NEXT tile's data;
// never drains to 0 in steady state (T3+T4). T2 XOR-swizzle via pre-swizzled
// global source; T5 setprio around the MFMA cluster.
// ---------------------------------------------------------------------------
template <int BN, int EPI>
__global__ __launch_bounds__(512, 2) void k_gemm8(const u16* __restrict__ A,
                                                  const u16* __restrict__ B,
                                                  void* __restrict__ Cv,
                                                  int M, int N, int K) {
  constexpr int HN = BN / 2;        // rows per B half-tile
  constexpr int CW = BN / 8;        // per-wave cols per half
  constexpr int FN = CW / 16;       // B frags per half (2 or 1)
  constexpr int LB = (HN * 64 * 2) / (512 * 16); // loads/thread per B ht (2 or 1)
  constexpr int VM = LB + 2;        // steady-state vmcnt

  __shared__ __align__(16) u16 lA[2][2][128 * 64];
  __shared__ __align__(16) u16 lB[2][2][HN * 64];

  const int tid = threadIdx.x;
  const int wid = tid >> 6, lane = tid & 63;
  const int g = lane >> 4, q = lane & 15;
  const int wm = wid >> 2, wn = wid & 3;
  const int l8 = lane >> 3, l7 = lane & 7;
  const int bmBase = blockIdx.y * 256;
  const int bnBase = blockIdx.x * BN;
  const int NT = K >> 6;

  const f32x4 fzero = {0.f, 0.f, 0.f, 0.f};
  f32x4 acc[2][2][4][FN];
#pragma unroll
  for (int ha = 0; ha < 2; ++ha)
#pragma unroll
    for (int hb = 0; hb < 2; ++hb)
#pragma unroll
      for (int fm = 0; fm < 4; ++fm)
#pragma unroll
        for (int fn = 0; fn < FN; ++fn) acc[ha][hb][fm][fn] = fzero;

  auto stageA = [&](int tile, int half, int bufI) {
    if (tile < NT) {
#pragma unroll
      for (int j = 0; j < 2; ++j) {
        int ch = wid * 2 + j;
        int r = ch * 8 + l8;
        int sc = (l7 * 8) ^ ((r & 7) << 3);
        g2l16(A + (size_t)(bmBase + half * 128 + r) * K + (size_t)tile * 64 + sc,
              &lA[bufI][half][ch * 512]);
      }
    }
  };
  auto stageB = [&](int tile, int half, int bufI) {
    if (tile < NT) {
#pragma unroll
      for (int j = 0; j < LB; ++j) {
        int ch = wid * LB + j;
        int r = ch * 8 + l8;
        int sc = (l7 * 8) ^ ((r & 7) << 3);
        g2l16(B + (size_t)(bnBase + half * HN + r) * K + (size_t)tile * 64 + sc,
              &lB[bufI][half][ch * 512]);
      }
    }
  };

  // Prologue: issue stream [B0(0),A1(0),B1(0),A0(0),B0(1),A1(1)], allow the
  // last 2 half-tiles (VM loads) to remain in flight.
  stageB(0, 0, 0); stageA(0, 1, 0); stageB(0, 1, 0); stageA(0, 0, 0);
  stageB(1, 0, 1); stageA(1, 1, 1);
  if constexpr (VM == 4) asm volatile("s_waitcnt vmcnt(4)" ::: "memory");
  else                   asm volatile("s_waitcnt vmcnt(3)" ::: "memory");
  BAR();

#define PHASE(HA, HB, STAGE_STMT, WAIT_STMT)                                         \
  do {                                                                               \
    bf16x8 af[4][2];                                                                 \
    bf16x8 bfr[FN][2];                                                               \
    _Pragma("unroll") for (int fm = 0; fm < 4; ++fm) {                               \
      int r = wm * 64 + fm * 16 + q;                                                 \
      _Pragma("unroll") for (int kk = 0; kk < 2; ++kk) {                             \
        int c = (kk * 32 + g * 8) ^ ((r & 7) << 3);                                  \
        af[fm][kk] = *(const bf16x8*)&lA[buf][HA][r * 64 + c];                       \
      }                                                                              \
    }                                                                                \
    _Pragma("unroll") for (int fn = 0; fn < FN; ++fn) {                              \
      int r = wn * CW + fn * 16 + q;                                                 \
      _Pragma("unroll") for (int kk = 0; kk < 2; ++kk) {                             \
        int c = (kk * 32 + g * 8) ^ ((r & 7) << 3);                                  \
        bfr[fn][kk] = *(const bf16x8*)&lB[buf][HB][r * 64 + c];                      \
      }                                                                              \
    }                                                                                \
    STAGE_STMT;                                                                      \
    WAIT_STMT;                                                                       \
    BAR();                                                                           \
    asm volatile("s_waitcnt lgkmcnt(0)" ::: "memory");                               \
    __builtin_amdgcn_sched_barrier(0);                                               \
    __builtin_amdgcn_s_setprio(1);                                                   \
    _Pragma("unroll") for (int fm = 0; fm < 4; ++fm)                                 \
      _Pragma("unroll") for (int fn = 0; fn < FN; ++fn) {                            \
        acc[HA][HB][fm][fn] = __builtin_amdgcn_mfma_f32_16x16x32_bf16(               \
            af[fm][0], bfr[fn][0], acc[HA][HB][fm][fn], 0, 0, 0);                    \
        acc[HA][HB][fm][fn] = __builtin_amdgcn_mfma_f32_16x16x32_bf16(               \
            af[fm][1], bfr[fn][1], acc[HA][HB][fm][fn], 0, 0, 0);                    \
      }                                                                              \
    __builtin_amdgcn_s_setprio(0);                                                   \
    asm volatile("" ::: "memory");                                                   \
    __builtin_amdgcn_s_barrier();                                                    \
    asm volatile("" ::: "memory");                                                   \
  } while (0)

  for (int t = 0; t < NT; ++t) {
    const int buf = t & 1;
    PHASE(0, 0, stageB(t + 1, 1, buf ^ 1), );
    PHASE(1, 0, stageA(t + 1, 0, buf ^ 1), );
    PHASE(1, 1, stageB(t + 2, 0, buf), );
    PHASE(0, 1, stageA(t + 2, 1, buf),
          if (t + 2 < NT) {
            if constexpr (VM == 4) asm volatile("s_waitcnt vmcnt(4)" ::: "memory");
            else                   asm volatile("s_waitcnt vmcnt(3)" ::: "memory");
          } else {
            asm volatile("s_waitcnt vmcnt(0)" ::: "memory");
          });
  }
#undef PHASE

  // Epilogue: C write
#pragma unroll
  for (int ha = 0; ha < 2; ++ha)
#pragma unroll
    for (int hb = 0; hb < 2; ++hb)
#pragma unroll
      for (int fm = 0; fm < 4; ++fm)
#pragma unroll
        for (int fn = 0; fn < FN; ++fn) {
          int col = bnBase + hb * HN + wn * CW + fn * 16 + q;
#pragma unroll
          for (int r = 0; r < 4; ++r) {
            int row = bmBase + ha * 128 + wm * 64 + fm * 16 + g * 4 + r;
            if (EPI == 0)
              ((u16*)Cv)[(size_t)row * N + col] = f2b(acc[ha][hb][fm][fn][r]);
            else
              ((float*)Cv)[(size_t)row * N + col] = acc[ha][hb][fm][fn][r];
          }
        }
}

// qkv [4096][6144] bf16 -> qr,kr [B*H][T][128] (RoPE applied, q scaled),
// vtb [B*H][128][T] (transposed V)
__global__ __launch_bounds__(256) void k_scatter_rope(const u16* __restrict__ qkv,
                                                      const float* __restrict__ cosb,
                                                      const float* __restrict__ sinb,
                                                      u16* __restrict__ qr,
                                                      u16* __restrict__ kr,
                                                      u16* __restrict__ vtb) {
  __shared__ __align__(16) u16 vtile[128][72];
  const int bh = blockIdx.x, b = bh >> 4, h = bh & 15;
  const int t0 = blockIdx.y * 64;
  const int tid = threadIdx.x;
  const float qscale = 0.08838834764831845f;
#pragma unroll
  for (int which = 0; which < 2; ++which) {
    u16* dst = which ? kr : qr;
    const int colbase = which * DMODEL + h * HD;
    const float sc = which ? 1.0f : qscale;
    for (int i = 0; i < 4; ++i) {
      int c = i * 256 + tid;
      int tt = c >> 4, d0 = (c & 15) * 8;
      int t = t0 + tt;
      size_t rowoff = (size_t)(b * T_SEQ + t) * NQKV + colbase;
      u16x8 xa = *(const u16x8*)(qkv + rowoff + d0);
      u16x8 xpart = *(const u16x8*)(qkv + rowoff + (d0 ^ 64));
      int dm = d0 & 63;
      bool lowhalf = d0 < 64;
      u16x8 y;
#pragma unroll
      for (int j = 0; j < 8; ++j) {
        float cv = cosb[t * 64 + dm + j];
        float sv = sinb[t * 64 + dm + j];
        float x0 = b2f(xa[j]), x1 = b2f(xpart[j]);
        float yv = lowhalf ? (x0 * cv - x1 * sv) : (x0 * cv + x1 * sv);
        y[j] = f2b(yv * sc);
      }
      *(u16x8*)(dst + ((size_t)bh * T_SEQ + t) * HD + d0) = y;
    }
  }
  for (int i = 0; i < 4; ++i) {
    int c = i * 256 + tid;
    int tt = c >> 4, d0 = (c & 15) * 8;
    size_t rowoff = (size_t)(b * T_SEQ + t0 + tt) * NQKV + 2 * DMODEL + h * HD;
    u16x8 xv = *(const u16x8*)(qkv + rowoff + d0);
#pragma unroll
    for (int j = 0; j < 8; ++j) vtile[d0 + j][tt] = xv[j];
  }
  __syncthreads();
  for (int i = 0; i < 4; ++i) {
    int c = i * 256 + tid;
    int d = c >> 3, tc = (c & 7) * 8;
    u16x8 y = *(const u16x8*)(&vtile[d][tc]);
    *(u16x8*)(vtb + ((size_t)bh * HD + d) * T_SEQ + t0 + tc) = y;
  }
}

// Flash attention: grid (B*H, T/64). 4 waves/block, each wave owns 16 q-rows.
__global__ __launch_bounds__(256) void k_attn(const u16* __restrict__ qr,
                                              const u16* __restrict__ kr,
                                              const u16* __restrict__ vtb,
                                              u16* __restrict__ ao) {
  __shared__ __align__(16) u16 lK[64 * 128];
  __shared__ __align__(16) u16 lV[128 * 64];
  __shared__ __align__(16) u16 lP[4][16 * 72];
  const int bh = blockIdx.x, b = bh >> 4, h = bh & 15;
  const int qt = blockIdx.y;
  const int tid = threadIdx.x;
  const int wid = tid >> 6, lane = tid & 63;
  const int g = lane >> 4, q = lane & 15;
  const int qw0 = qt * 64 + wid * 16;
  const u16* qb = qr + (size_t)bh * T_SEQ * HD;
  const u16* kbp = kr + (size_t)bh * T_SEQ * HD;
  const u16* vb = vtb + (size_t)bh * HD * T_SEQ;
  const f32x4 fzero = {0.f, 0.f, 0.f, 0.f};

  bf16x8 qf[4];
#pragma unroll
  for (int ks = 0; ks < 4; ++ks)
    qf[ks] = *(const bf16x8*)(qb + (size_t)(qw0 + q) * HD + ks * 32 + g * 8);

  f32x4 o_acc[8];
#pragma unroll
  for (int n = 0; n < 8; ++n) o_acc[n] = fzero;
  float m_run = -1e30f, l_run = 0.f;

  const int ntiles = qt + 1;
  for (int kt = 0; kt < ntiles; ++kt) {
    const int kb = kt * 64;
    __syncthreads();
#pragma unroll
    for (int i = 0; i < 4; ++i) {
      int chunk = wid * 4 + i;
      int row = chunk * 4 + g;
      int scol = (q * 8) ^ ((row & 7) << 3);
      g2l16(kbp + (size_t)(kb + row) * HD + scol, lK + chunk * 512);
    }
#pragma unroll
    for (int i = 0; i < 4; ++i) {
      int chunk = wid * 4 + i;
      int row = chunk * 8 + (lane >> 3);
      int scol = ((lane & 7) * 8) ^ ((row & 7) << 3);
      g2l16(vb + (size_t)row * T_SEQ + kb + scol, lV + chunk * 512);
    }
    __syncthreads();
    {
      f32x4 st[4];
#pragma unroll
      for (int m = 0; m < 4; ++m) st[m] = fzero;
#pragma unroll
      for (int ks = 0; ks < 4; ++ks) {
#pragma unroll
        for (int m = 0; m < 4; ++m) {
          int row = m * 16 + q;
          int col = (ks * 32 + g * 8) ^ ((row & 7) << 3);
          bf16x8 kf = *(const bf16x8*)(lK + row * 128 + col);
          st[m] = __builtin_amdgcn_mfma_f32_16x16x32_bf16(kf, qf[ks], st[m], 0, 0, 0);
        }
      }
      const int qrow = qw0 + q;
      float p[4][4];
      float pmax = -1e30f;
#pragma unroll
      for (int m = 0; m < 4; ++m)
#pragma unroll
        for (int r = 0; r < 4; ++r) {
          int kcol = kb + m * 16 + g * 4 + r;
          float s = (kcol <= qrow) ? st[m][r] : -1e30f;
          p[m][r] = s;
          pmax = fmaxf(pmax, s);
        }
      pmax = fmaxf(pmax, __shfl_xor(pmax, 16));
      pmax = fmaxf(pmax, __shfl_xor(pmax, 32));
      float m_new = fmaxf(m_run, pmax);
      float corr = __expf(m_run - m_new);
      float ls = 0.f;
#pragma unroll
      for (int m = 0; m < 4; ++m)
#pragma unroll
        for (int r = 0; r < 4; ++r) {
          float e = __expf(p[m][r] - m_new);
          p[m][r] = e;
          ls += e;
        }
      ls += __shfl_xor(ls, 16);
      ls += __shfl_xor(ls, 32);
      l_run = l_run * corr + ls;
      m_run = m_new;
#pragma unroll
      for (int m = 0; m < 4; ++m) {
#pragma unroll
        for (int rp = 0; rp < 2; ++rp) {
          u32 pk = (u32)f2b(p[m][rp * 2]) | ((u32)f2b(p[m][rp * 2 + 1]) << 16);
          *(u32*)(&lP[wid][q * 72 + m * 16 + g * 4 + rp * 2]) = pk;
        }
      }
      asm volatile("s_waitcnt lgkmcnt(0)" ::: "memory");
      __builtin_amdgcn_sched_barrier(0);
      float corr4[4];
#pragma unroll
      for (int r = 0; r < 4; ++r) corr4[r] = __shfl(corr, g * 4 + r);
#pragma unroll
      for (int n = 0; n < 8; ++n) {
#pragma unroll
        for (int r = 0; r < 4; ++r) o_acc[n][r] *= corr4[r];
      }
#pragma unroll
      for (int ks = 0; ks < 2; ++ks) {
        bf16x8 pf = *(const bf16x8*)(&lP[wid][q * 72 + ks * 32 + g * 8]);
#pragma unroll
        for (int n = 0; n < 8; ++n) {
          int row = n * 16 + q;
          int col = (ks * 32 + g * 8) ^ ((row & 7) << 3);
          bf16x8 vf = *(const bf16x8*)(lV + row * 64 + col);
          o_acc[n] = __builtin_amdgcn_mfma_f32_16x16x32_bf16(pf, vf, o_acc[n], 0, 0, 0);
        }
      }
    }
  }
  float linv[4];
#pragma unroll
  for (int r = 0; r < 4; ++r) {
    float lv = __shfl(l_run, g * 4 + r);
    linv[r] = 1.0f / lv;
  }
#pragma unroll
  for (int n = 0; n < 8; ++n)
#pragma unroll
    for (int r = 0; r < 4; ++r) {
      int trow = qw0 + g * 4 + r;
      ao[(size_t)(b * T_SEQ + trow) * DMODEL + h * HD + n * 16 + q] = f2b(o_acc[n][r] * linv[r]);
    }
}

extern "C" void kernel_launch(void* const* d_in, const int* in_sizes, int n_in,
                              void* d_out, int out_size, void* d_ws, size_t ws_size,
                              hipStream_t stream) {
  const float* x = (const float*)d_in[0];
  const float* w_qkv = (const float*)d_in[1];
  const float* w_out = (const float*)d_in[2];
  char* ws = (char*)d_ws;
  size_t off = 0;
  u16* xb = (u16*)(ws + off);    off += (size_t)MROWS * DMODEL * 2;   // also reused as ao
  u16* wqkvT = (u16*)(ws + off); off += (size_t)NQKV * DMODEL * 2;
  u16* woutT = (u16*)(ws + off); off += (size_t)DMODEL * DMODEL * 2;
  u16* qkv = (u16*)(ws + off);   off += (size_t)MROWS * NQKV * 2;
  u16* qr = (u16*)(ws + off);    off += (size_t)32 * T_SEQ * HD * 2;
  u16* kr = (u16*)(ws + off);    off += (size_t)32 * T_SEQ * HD * 2;
  u16* vtb = (u16*)(ws + off);   off += (size_t)32 * T_SEQ * HD * 2;
  float* cosb = (float*)(ws + off); off += (size_t)T_SEQ * 64 * 4;
  float* sinb = (float*)(ws + off); off += (size_t)T_SEQ * 64 * 4;
  u16* ao = xb;

  k_f32_to_bf16<<<dim3(MROWS * DMODEL / (256 * 8)), 256, 0, stream>>>(x, xb, MROWS * DMODEL);
  k_transpose_bf16<<<dim3(NQKV / 32, DMODEL / 32), 256, 0, stream>>>(w_qkv, wqkvT, DMODEL, NQKV);
  k_transpose_bf16<<<dim3(DMODEL / 32, DMODEL / 32), 256, 0, stream>>>(w_out, woutT, DMODEL, DMODEL);
  k_rope_cache<<<dim3(T_SEQ * 64 / 256), 256, 0, stream>>>(cosb, sinb);
  k_gemm8<256, 0><<<dim3(NQKV / 256, MROWS / 256), 512, 0, stream>>>(xb, wqkvT, qkv, MROWS, NQKV, DMODEL);
  k_scatter_rope<<<dim3(32, T_SEQ / 64), 256, 0, stream>>>(qkv, cosb, sinb, qr, kr, vtb);
  k_attn<<<dim3(32, T_SEQ / 64), 256, 0, stream>>>(qr, kr, vtb, ao);
  k_gemm8<128, 1><<<dim3(DMODEL / 128, MROWS / 256), 512, 0, stream>>>(ao, woutT, d_out, MROWS, DMODEL, DMODEL);
}

// Round 4
// 282.475 us; speedup vs baseline: 1.1605x; 1.1605x over previous
//
#include <hip/hip_runtime.h>

typedef unsigned short u16;
typedef unsigned int u32;
typedef __bf16 bf16x8 __attribute__((ext_vector_type(8)));
typedef float f32x4 __attribute__((ext_vector_type(4)));
typedef u16 u16x8 __attribute__((ext_vector_type(8)));

#define T_SEQ 2048
#define DMODEL 2048
#define NQKV 6144
#define HD 128
#define NH 16
#define MROWS 4096

__device__ __forceinline__ u16 f2b(float f) {
  union { float f; u32 u; } a; a.f = f;
  u32 r = a.u + 0x7fffu + ((a.u >> 16) & 1u);
  return (u16)(r >> 16);
}
__device__ __forceinline__ float b2f(u16 h) {
  union { u32 u; float f; } a; a.u = ((u32)h) << 16;
  return a.f;
}
__device__ __forceinline__ void g2l16(const u16* g, u16* l) {
  __builtin_amdgcn_global_load_lds((const __attribute__((address_space(1))) u32*)g,
                                   (__attribute__((address_space(3))) u32*)l, 16, 0, 0);
}

#define BAR() do { asm volatile("" ::: "memory"); __builtin_amdgcn_s_barrier(); asm volatile("" ::: "memory"); } while (0)

__global__ void k_f32_to_bf16(const float* __restrict__ in, u16* __restrict__ out, int n) {
  int i = (blockIdx.x * 256 + threadIdx.x) * 8;
  if (i >= n) return;
  float4 a = *(const float4*)(in + i);
  float4 b = *(const float4*)(in + i + 4);
  u16x8 v;
  v[0] = f2b(a.x); v[1] = f2b(a.y); v[2] = f2b(a.z); v[3] = f2b(a.w);
  v[4] = f2b(b.x); v[5] = f2b(b.y); v[6] = f2b(b.z); v[7] = f2b(b.w);
  *(u16x8*)(out + i) = v;
}

// out[c][r] = bf16(in[r][c]); in is R x C f32
__global__ void k_transpose_bf16(const float* __restrict__ in, u16* __restrict__ out,
                                 int R, int C) {
  __shared__ u16 tile[32][33];
  const int c0 = blockIdx.x * 32, r0 = blockIdx.y * 32;
  const int tx = threadIdx.x & 31, ty = threadIdx.x >> 5;
#pragma unroll
  for (int i = 0; i < 32; i += 8)
    tile[ty + i][tx] = f2b(in[(size_t)(r0 + ty + i) * C + c0 + tx]);
  __syncthreads();
#pragma unroll
  for (int i = 0; i < 32; i += 8)
    out[(size_t)(c0 + ty + i) * R + r0 + tx] = tile[tx][ty + i];
}

__global__ void k_rope_cache(float* __restrict__ cosb, float* __restrict__ sinb) {
  int idx = blockIdx.x * 256 + threadIdx.x;
  int t = idx >> 6, d = idx & 63;
  float inv = powf(10000.0f, -(float)d * (1.0f / 64.0f));
  float fr = (float)t * inv;
  cosb[idx] = cosf(fr);
  sinb[idx] = sinf(fr);
}

// ---------------------------------------------------------------------------
// 8-phase GEMM, 256x256 tile, BK=64, 8 waves, cross-phase fragment reuse:
//   ph0:(A0,B0) read A0->aE, B0->bF   | stage B1(t+1)->lB[buf^1][1]
//   ph1:(A1,B0) read A1->aO           | stage A0(t+1)->lA[buf^1][0]
//   ph2:(A1,B1) read B1->bF           | stage B0(t+2)->lB[buf][0]
//   ph3:(A0,B1) no reads (aE,bF live) | stage A1(t+2)->lA[buf][1], vmcnt(4)
// STAGE LEDGER (the round-3 NaN): B0/A1 are staged TWO tiles ahead, so the
// prologue must stage tile0's 4 half-tiles AND B0(1),A1(1). vmcnt(4) at each
// ph3 completes exactly the next tile's 4 half-tiles (8 oldest of 12 loads).
// ---------------------------------------------------------------------------
template <int EPI>
__global__ __launch_bounds__(512, 2) void k_gemm8(const u16* __restrict__ A,
                                                  const u16* __restrict__ B,
                                                  void* __restrict__ Cv,
                                                  int M, int N, int K) {
  __shared__ __align__(16) u16 lA[2][2][128 * 64];
  __shared__ __align__(16) u16 lB[2][2][128 * 64];

  const int tid = threadIdx.x;
  const int wid = tid >> 6, lane = tid & 63;
  const int g = lane >> 4, q = lane & 15;
  const int wm = wid >> 2, wn = wid & 3;
  const int l8 = lane >> 3, l7 = lane & 7;
  const int bmBase = blockIdx.y * 256;
  const int bnBase = blockIdx.x * 256;
  const int NT = K >> 6;

  const f32x4 fzero = {0.f, 0.f, 0.f, 0.f};
  f32x4 acc[2][2][4][2];
#pragma unroll
  for (int ha = 0; ha < 2; ++ha)
#pragma unroll
    for (int hb = 0; hb < 2; ++hb)
#pragma unroll
      for (int fm = 0; fm < 4; ++fm)
#pragma unroll
        for (int fn = 0; fn < 2; ++fn) acc[ha][hb][fm][fn] = fzero;

  auto stageA = [&](int tile, int half, int bufI) {
    if (tile < NT) {
#pragma unroll
      for (int j = 0; j < 2; ++j) {
        int ch = wid * 2 + j;
        int r = ch * 8 + l8;
        int sc = (l7 * 8) ^ ((r & 7) << 3);
        g2l16(A + (size_t)(bmBase + half * 128 + r) * K + (size_t)tile * 64 + sc,
              &lA[bufI][half][ch * 512]);
      }
    }
  };
  auto stageB = [&](int tile, int half, int bufI) {
    if (tile < NT) {
#pragma unroll
      for (int j = 0; j < 2; ++j) {
        int ch = wid * 2 + j;
        int r = ch * 8 + l8;
        int sc = (l7 * 8) ^ ((r & 7) << 3);
        g2l16(B + (size_t)(bnBase + half * 128 + r) * K + (size_t)tile * 64 + sc,
              &lB[bufI][half][ch * 512]);
      }
    }
  };

  bf16x8 aE[8], aO[8], bF[4];

#define READ_A(dst, HA)                                                              \
  _Pragma("unroll") for (int fm = 0; fm < 4; ++fm) {                                 \
    int r = wm * 64 + fm * 16 + q;                                                   \
    _Pragma("unroll") for (int kk = 0; kk < 2; ++kk) {                               \
      int c = (kk * 32 + g * 8) ^ ((r & 7) << 3);                                    \
      dst[fm * 2 + kk] = *(const bf16x8*)&lA[buf][HA][r * 64 + c];                   \
    }                                                                                \
  }
#define READ_B(HB)                                                                   \
  _Pragma("unroll") for (int fn = 0; fn < 2; ++fn) {                                 \
    int r = wn * 32 + fn * 16 + q;                                                   \
    _Pragma("unroll") for (int kk = 0; kk < 2; ++kk) {                               \
      int c = (kk * 32 + g * 8) ^ ((r & 7) << 3);                                    \
      bF[fn * 2 + kk] = *(const bf16x8*)&lB[buf][HB][r * 64 + c];                    \
    }                                                                                \
  }
#define MFMA_Q(HA, HB, asrc)                                                         \
  __builtin_amdgcn_s_setprio(1);                                                     \
  _Pragma("unroll") for (int fm = 0; fm < 4; ++fm)                                   \
    _Pragma("unroll") for (int fn = 0; fn < 2; ++fn) {                               \
      acc[HA][HB][fm][fn] = __builtin_amdgcn_mfma_f32_16x16x32_bf16(                 \
          asrc[fm * 2 + 0], bF[fn * 2 + 0], acc[HA][HB][fm][fn], 0, 0, 0);           \
      acc[HA][HB][fm][fn] = __builtin_amdgcn_mfma_f32_16x16x32_bf16(                 \
          asrc[fm * 2 + 1], bF[fn * 2 + 1], acc[HA][HB][fm][fn], 0, 0, 0);           \
    }                                                                                \
  __builtin_amdgcn_s_setprio(0);
#define LGKM0() do { asm volatile("s_waitcnt lgkmcnt(0)" ::: "memory"); \
                     __builtin_amdgcn_sched_barrier(0); } while (0)

  // Prologue: tile 0's four half-tiles PLUS the two-ahead halves B0(1), A1(1).
  // 12 loads in flight; vmcnt(4) completes the oldest 8 (= all of tile 0).
  stageB(0, 0, 0); stageA(0, 0, 0); stageA(0, 1, 0); stageB(0, 1, 0);
  stageB(1, 0, 1); stageA(1, 1, 1);
  asm volatile("s_waitcnt vmcnt(4)" ::: "memory");
  BAR();

  for (int t = 0; t < NT; ++t) {
    const int buf = t & 1;
    // ph0: (A0,B0)
    READ_A(aE, 0); READ_B(0);
    stageB(t + 1, 1, buf ^ 1);
    BAR(); LGKM0();
    MFMA_Q(0, 0, aE);
    BAR();
    // ph1: (A1,B0)
    READ_A(aO, 1);
    stageA(t + 1, 0, buf ^ 1);
    BAR(); LGKM0();
    MFMA_Q(1, 0, aO);
    BAR();
    // ph2: (A1,B1)
    READ_B(1);
    stageB(t + 2, 0, buf);
    BAR(); LGKM0();
    MFMA_Q(1, 1, aO);
    BAR();
    // ph3: (A0,B1) — no LDS reads; counted vmcnt once per K-tile
    stageA(t + 2, 1, buf);
    if (t + 2 < NT) asm volatile("s_waitcnt vmcnt(4)" ::: "memory");
    else            asm volatile("s_waitcnt vmcnt(0)" ::: "memory");
    BAR();
    MFMA_Q(0, 1, aE);
    BAR();
  }
#undef READ_A
#undef READ_B
#undef MFMA_Q
#undef LGKM0

#pragma unroll
  for (int ha = 0; ha < 2; ++ha)
#pragma unroll
    for (int hb = 0; hb < 2; ++hb)
#pragma unroll
      for (int fm = 0; fm < 4; ++fm)
#pragma unroll
        for (int fn = 0; fn < 2; ++fn) {
          int col = bnBase + hb * 128 + wn * 32 + fn * 16 + q;
#pragma unroll
          for (int r = 0; r < 4; ++r) {
            int row = bmBase + ha * 128 + wm * 64 + fm * 16 + g * 4 + r;
            if (EPI == 0)
              ((u16*)Cv)[(size_t)row * N + col] = f2b(acc[ha][hb][fm][fn][r]);
            else
              ((float*)Cv)[(size_t)row * N + col] = acc[ha][hb][fm][fn][r];
          }
        }
}

// m97-style 128x128 GEMM (round-1 proven) for the output projection.
template <int EPI>
__global__ __launch_bounds__(256) void k_gemm_nt(const u16* __restrict__ A,
                                                 const u16* __restrict__ B,
                                                 void* __restrict__ Cv,
                                                 int M, int N, int K) {
  __shared__ __align__(16) u16 lA[128 * 64];
  __shared__ __align__(16) u16 lB[128 * 64];
  const int tid = threadIdx.x;
  const int wid = tid >> 6, lane = tid & 63;
  const int g = lane >> 4, q = lane & 15;
  const int wr = wid >> 1, wc = wid & 1;
  const int bn = blockIdx.x, bm = blockIdx.y;
  const int l8 = lane >> 3, l7 = lane & 7;
  const f32x4 fzero = {0.f, 0.f, 0.f, 0.f};
  f32x4 acc[4][4];
#pragma unroll
  for (int m = 0; m < 4; ++m)
#pragma unroll
    for (int n = 0; n < 4; ++n) acc[m][n] = fzero;

  const u16* Ab = A + (size_t)bm * 128 * K;
  const u16* Bb = B + (size_t)bn * 128 * K;

  for (int k0 = 0; k0 < K; k0 += 64) {
    __syncthreads();
#pragma unroll
    for (int i = 0; i < 4; ++i) {
      int chunk = wid * 4 + i;
      int row = chunk * 8 + l8;
      int scol = (l7 * 8) ^ ((row & 7) << 3);
      g2l16(Ab + (size_t)row * K + k0 + scol, lA + chunk * 512);
      g2l16(Bb + (size_t)row * K + k0 + scol, lB + chunk * 512);
    }
    __syncthreads();
#pragma unroll
    for (int kk = 0; kk < 2; ++kk) {
      bf16x8 af[4], bfr[4];
#pragma unroll
      for (int m = 0; m < 4; ++m) {
        int row = wr * 64 + m * 16 + q;
        int col = (kk * 32 + g * 8) ^ ((row & 7) << 3);
        af[m] = *(const bf16x8*)(lA + row * 64 + col);
      }
#pragma unroll
      for (int n = 0; n < 4; ++n) {
        int row = wc * 64 + n * 16 + q;
        int col = (kk * 32 + g * 8) ^ ((row & 7) << 3);
        bfr[n] = *(const bf16x8*)(lB + row * 64 + col);
      }
#pragma unroll
      for (int m = 0; m < 4; ++m)
#pragma unroll
        for (int n = 0; n < 4; ++n)
          acc[m][n] = __builtin_amdgcn_mfma_f32_16x16x32_bf16(af[m], bfr[n], acc[m][n], 0, 0, 0);
    }
  }
  const int rbase = bm * 128 + wr * 64;
  const int cbase = bn * 128 + wc * 64;
#pragma unroll
  for (int m = 0; m < 4; ++m)
#pragma unroll
    for (int n = 0; n < 4; ++n) {
      int col = cbase + n * 16 + q;
#pragma unroll
      for (int r = 0; r < 4; ++r) {
        int row = rbase + m * 16 + g * 4 + r;
        if (EPI == 0)
          ((u16*)Cv)[(size_t)row * N + col] = f2b(acc[m][n][r]);
        else
          ((float*)Cv)[(size_t)row * N + col] = acc[m][n][r];
      }
    }
}

// qkv [4096][6144] bf16 -> qr,kr [B*H][T][128] (RoPE applied, q scaled),
// vtb [B*H][128][T] (transposed V)
__global__ __launch_bounds__(256) void k_scatter_rope(const u16* __restrict__ qkv,
                                                      const float* __restrict__ cosb,
                                                      const float* __restrict__ sinb,
                                                      u16* __restrict__ qr,
                                                      u16* __restrict__ kr,
                                                      u16* __restrict__ vtb) {
  __shared__ __align__(16) u16 vtile[128][72];
  const int bh = blockIdx.x, b = bh >> 4, h = bh & 15;
  const int t0 = blockIdx.y * 64;
  const int tid = threadIdx.x;
  const float qscale = 0.08838834764831845f;
#pragma unroll
  for (int which = 0; which < 2; ++which) {
    u16* dst = which ? kr : qr;
    const int colbase = which * DMODEL + h * HD;
    const float sc = which ? 1.0f : qscale;
    for (int i = 0; i < 4; ++i) {
      int c = i * 256 + tid;
      int tt = c >> 4, d0 = (c & 15) * 8;
      int t = t0 + tt;
      size_t rowoff = (size_t)(b * T_SEQ + t) * NQKV + colbase;
      u16x8 xa = *(const u16x8*)(qkv + rowoff + d0);
      u16x8 xpart = *(const u16x8*)(qkv + rowoff + (d0 ^ 64));
      int dm = d0 & 63;
      bool lowhalf = d0 < 64;
      u16x8 y;
#pragma unroll
      for (int j = 0; j < 8; ++j) {
        float cv = cosb[t * 64 + dm + j];
        float sv = sinb[t * 64 + dm + j];
        float x0 = b2f(xa[j]), x1 = b2f(xpart[j]);
        float yv = lowhalf ? (x0 * cv - x1 * sv) : (x0 * cv + x1 * sv);
        y[j] = f2b(yv * sc);
      }
      *(u16x8*)(dst + ((size_t)bh * T_SEQ + t) * HD + d0) = y;
    }
  }
  for (int i = 0; i < 4; ++i) {
    int c = i * 256 + tid;
    int tt = c >> 4, d0 = (c & 15) * 8;
    size_t rowoff = (size_t)(b * T_SEQ + t0 + tt) * NQKV + 2 * DMODEL + h * HD;
    u16x8 xv = *(const u16x8*)(qkv + rowoff + d0);
#pragma unroll
    for (int j = 0; j < 8; ++j) vtile[d0 + j][tt] = xv[j];
  }
  __syncthreads();
  for (int i = 0; i < 4; ++i) {
    int c = i * 256 + tid;
    int d = c >> 3, tc = (c & 7) * 8;
    u16x8 y = *(const u16x8*)(&vtile[d][tc]);
    *(u16x8*)(vtb + ((size_t)bh * HD + d) * T_SEQ + t0 + tc) = y;
  }
}

// Flash attention: grid (B*H, T/64). 4 waves/block, each wave owns 16 q-rows.
// Long q-tiles launch first (reverse qt) to smooth the causal tail.
__global__ __launch_bounds__(256) void k_attn(const u16* __restrict__ qr,
                                              const u16* __restrict__ kr,
                                              const u16* __restrict__ vtb,
                                              u16* __restrict__ ao) {
  __shared__ __align__(16) u16 lK[64 * 128];
  __shared__ __align__(16) u16 lV[128 * 64];
  __shared__ __align__(16) u16 lP[4][16 * 72];
  const int bh = blockIdx.x, b = bh >> 4, h = bh & 15;
  const int qt = (T_SEQ / 64 - 1) - blockIdx.y;
  const int tid = threadIdx.x;
  const int wid = tid >> 6, lane = tid & 63;
  const int g = lane >> 4, q = lane & 15;
  const int qw0 = qt * 64 + wid * 16;
  const u16* qb = qr + (size_t)bh * T_SEQ * HD;
  const u16* kbp = kr + (size_t)bh * T_SEQ * HD;
  const u16* vb = vtb + (size_t)bh * HD * T_SEQ;
  const f32x4 fzero = {0.f, 0.f, 0.f, 0.f};

  bf16x8 qf[4];
#pragma unroll
  for (int ks = 0; ks < 4; ++ks)
    qf[ks] = *(const bf16x8*)(qb + (size_t)(qw0 + q) * HD + ks * 32 + g * 8);

  f32x4 o_acc[8];
#pragma unroll
  for (int n = 0; n < 8; ++n) o_acc[n] = fzero;
  float m_run = -1e30f, l_run = 0.f;

  const int ntiles = qt + 1;
  for (int kt = 0; kt < ntiles; ++kt) {
    const int kb = kt * 64;
    __syncthreads();
#pragma unroll
    for (int i = 0; i < 4; ++i) {
      int chunk = wid * 4 + i;
      int row = chunk * 4 + g;
      int scol = (q * 8) ^ ((row & 7) << 3);
      g2l16(kbp + (size_t)(kb + row) * HD + scol, lK + chunk * 512);
    }
#pragma unroll
    for (int i = 0; i < 4; ++i) {
      int chunk = wid * 4 + i;
      int row = chunk * 8 + (lane >> 3);
      int scol = ((lane & 7) * 8) ^ ((row & 7) << 3);
      g2l16(vb + (size_t)row * T_SEQ + kb + scol, lV + chunk * 512);
    }
    __syncthreads();
    {
      f32x4 st[4];
#pragma unroll
      for (int m = 0; m < 4; ++m) st[m] = fzero;
#pragma unroll
      for (int ks = 0; ks < 4; ++ks) {
#pragma unroll
        for (int m = 0; m < 4; ++m) {
          int row = m * 16 + q;
          int col = (ks * 32 + g * 8) ^ ((row & 7) << 3);
          bf16x8 kf = *(const bf16x8*)(lK + row * 128 + col);
          st[m] = __builtin_amdgcn_mfma_f32_16x16x32_bf16(kf, qf[ks], st[m], 0, 0, 0);
        }
      }
      const int qrow = qw0 + q;
      float p[4][4];
      float pmax = -1e30f;
#pragma unroll
      for (int m = 0; m < 4; ++m)
#pragma unroll
        for (int r = 0; r < 4; ++r) {
          int kcol = kb + m * 16 + g * 4 + r;
          float s = (kcol <= qrow) ? st[m][r] : -1e30f;
          p[m][r] = s;
          pmax = fmaxf(pmax, s);
        }
      pmax = fmaxf(pmax, __shfl_xor(pmax, 16));
      pmax = fmaxf(pmax, __shfl_xor(pmax, 32));
      float m_new = fmaxf(m_run, pmax);
      float corr = __expf(m_run - m_new);
      float ls = 0.f;
#pragma unroll
      for (int m = 0; m < 4; ++m)
#pragma unroll
        for (int r = 0; r < 4; ++r) {
          float e = __expf(p[m][r] - m_new);
          p[m][r] = e;
          ls += e;
        }
      ls += __shfl_xor(ls, 16);
      ls += __shfl_xor(ls, 32);
      l_run = l_run * corr + ls;
      m_run = m_new;
#pragma unroll
      for (int m = 0; m < 4; ++m) {
#pragma unroll
        for (int rp = 0; rp < 2; ++rp) {
          u32 pk = (u32)f2b(p[m][rp * 2]) | ((u32)f2b(p[m][rp * 2 + 1]) << 16);
          *(u32*)(&lP[wid][q * 72 + m * 16 + g * 4 + rp * 2]) = pk;
        }
      }
      asm volatile("s_waitcnt lgkmcnt(0)" ::: "memory");
      __builtin_amdgcn_sched_barrier(0);
      float corr4[4];
#pragma unroll
      for (int r = 0; r < 4; ++r) corr4[r] = __shfl(corr, g * 4 + r);
#pragma unroll
      for (int n = 0; n < 8; ++n) {
#pragma unroll
        for (int r = 0; r < 4; ++r) o_acc[n][r] *= corr4[r];
      }
#pragma unroll
      for (int ks = 0; ks < 2; ++ks) {
        bf16x8 pf = *(const bf16x8*)(&lP[wid][q * 72 + ks * 32 + g * 8]);
#pragma unroll
        for (int n = 0; n < 8; ++n) {
          int row = n * 16 + q;
          int col = (ks * 32 + g * 8) ^ ((row & 7) << 3);
          bf16x8 vf = *(const bf16x8*)(lV + row * 64 + col);
          o_acc[n] = __builtin_amdgcn_mfma_f32_16x16x32_bf16(pf, vf, o_acc[n], 0, 0, 0);
        }
      }
    }
  }
  float linv[4];
#pragma unroll
  for (int r = 0; r < 4; ++r) {
    float lv = __shfl(l_run, g * 4 + r);
    linv[r] = 1.0f / lv;
  }
#pragma unroll
  for (int n = 0; n < 8; ++n)
#pragma unroll
    for (int r = 0; r < 4; ++r) {
      int trow = qw0 + g * 4 + r;
      ao[(size_t)(b * T_SEQ + trow) * DMODEL + h * HD + n * 16 + q] = f2b(o_acc[n][r] * linv[r]);
    }
}

extern "C" void kernel_launch(void* const* d_in, const int* in_sizes, int n_in,
                              void* d_out, int out_size, void* d_ws, size_t ws_size,
                              hipStream_t stream) {
  const float* x = (const float*)d_in[0];
  const float* w_qkv = (const float*)d_in[1];
  const float* w_out = (const float*)d_in[2];
  char* ws = (char*)d_ws;
  size_t off = 0;
  u16* xb = (u16*)(ws + off);    off += (size_t)MROWS * DMODEL * 2;   // also reused as ao
  u16* wqkvT = (u16*)(ws + off); off += (size_t)NQKV * DMODEL * 2;
  u16* woutT = (u16*)(ws + off); off += (size_t)DMODEL * DMODEL * 2;
  u16* qkv = (u16*)(ws + off);   off += (size_t)MROWS * NQKV * 2;
  u16* qr = (u16*)(ws + off);    off += (size_t)32 * T_SEQ * HD * 2;
  u16* kr = (u16*)(ws + off);    off += (size_t)32 * T_SEQ * HD * 2;
  u16* vtb = (u16*)(ws + off);   off += (size_t)32 * T_SEQ * HD * 2;
  float* cosb = (float*)(ws + off); off += (size_t)T_SEQ * 64 * 4;
  float* sinb = (float*)(ws + off); off += (size_t)T_SEQ * 64 * 4;
  u16* ao = xb;

  k_f32_to_bf16<<<dim3(MROWS * DMODEL / (256 * 8)), 256, 0, stream>>>(x, xb, MROWS * DMODEL);
  k_transpose_bf16<<<dim3(NQKV / 32, DMODEL / 32), 256, 0, stream>>>(w_qkv, wqkvT, DMODEL, NQKV);
  k_transpose_bf16<<<dim3(DMODEL / 32, DMODEL / 32), 256, 0, stream>>>(w_out, woutT, DMODEL, DMODEL);
  k_rope_cache<<<dim3(T_SEQ * 64 / 256), 256, 0, stream>>>(cosb, sinb);
  k_gemm8<0><<<dim3(NQKV / 256, MROWS / 256), 512, 0, stream>>>(xb, wqkvT, qkv, MROWS, NQKV, DMODEL);
  k_scatter_rope<<<dim3(32, T_SEQ / 64), 256, 0, stream>>>(qkv, cosb, sinb, qr, kr, vtb);
  k_attn<<<dim3(32, T_SEQ / 64), 256, 0, stream>>>(qr, kr, vtb, ao);
  k_gemm_nt<1><<<dim3(DMODEL / 128, MROWS / 128), 256, 0, stream>>>(ao, woutT, d_out, MROWS, DMODEL, DMODEL);
}

// Round 5
// 264.876 us; speedup vs baseline: 1.2376x; 1.0664x over previous
//
#include <hip/hip_runtime.h>

typedef unsigned short u16;
typedef unsigned int u32;
typedef __bf16 bf16x8 __attribute__((ext_vector_type(8)));
typedef float f32x4 __attribute__((ext_vector_type(4)));
typedef u16 u16x4 __attribute__((ext_vector_type(4)));
typedef u16 u16x8 __attribute__((ext_vector_type(8)));

#define T_SEQ 2048
#define DMODEL 2048
#define NQKV 6144
#define HD 128
#define NH 16
#define MROWS 4096

__device__ __forceinline__ u16 f2b(float f) {
  union { float f; u32 u; } a; a.f = f;
  u32 r = a.u + 0x7fffu + ((a.u >> 16) & 1u);
  return (u16)(r >> 16);
}
__device__ __forceinline__ float b2f(u16 h) {
  union { u32 u; float f; } a; a.u = ((u32)h) << 16;
  return a.f;
}
__device__ __forceinline__ void g2l16(const u16* g, u16* l) {
  __builtin_amdgcn_global_load_lds((const __attribute__((address_space(1))) u32*)g,
                                   (__attribute__((address_space(3))) u32*)l, 16, 0, 0);
}

__global__ void k_f32_to_bf16(const float* __restrict__ in, u16* __restrict__ out, int n) {
  int i = (blockIdx.x * 256 + threadIdx.x) * 8;
  if (i >= n) return;
  float4 a = *(const float4*)(in + i);
  float4 b = *(const float4*)(in + i + 4);
  u16x8 v;
  v[0] = f2b(a.x); v[1] = f2b(a.y); v[2] = f2b(a.z); v[3] = f2b(a.w);
  v[4] = f2b(b.x); v[5] = f2b(b.y); v[6] = f2b(b.z); v[7] = f2b(b.w);
  *(u16x8*)(out + i) = v;
}

// out[c][r] = bf16(in[r][c]); in is R x C f32
__global__ void k_transpose_bf16(const float* __restrict__ in, u16* __restrict__ out,
                                 int R, int C) {
  __shared__ u16 tile[32][33];
  const int c0 = blockIdx.x * 32, r0 = blockIdx.y * 32;
  const int tx = threadIdx.x & 31, ty = threadIdx.x >> 5;
#pragma unroll
  for (int i = 0; i < 32; i += 8)
    tile[ty + i][tx] = f2b(in[(size_t)(r0 + ty + i) * C + c0 + tx]);
  __syncthreads();
#pragma unroll
  for (int i = 0; i < 32; i += 8)
    out[(size_t)(c0 + ty + i) * R + r0 + tx] = tile[tx][ty + i];
}

__global__ void k_rope_cache(float* __restrict__ cosb, float* __restrict__ sinb) {
  int idx = blockIdx.x * 256 + threadIdx.x;
  int t = idx >> 6, d = idx & 63;
  float inv = powf(10000.0f, -(float)d * (1.0f / 64.0f));
  float fr = (float)t * inv;
  cosb[idx] = cosf(fr);
  sinb[idx] = sinf(fr);
}

// ---------------------------------------------------------------------------
// QKV GEMM with FUSED RoPE + head-scatter epilogue. m97 128x128 structure
// (round-1 proven, 884 TF). Key twist: wave's B-columns are the PAIRS
// (d, d+64) of one head: col(n) = wc*32 + (n&1)*16 + (n>>1)*64 + q.
// So RoPE's partner element acc[m][n^2] is IN THE SAME THREAD -> fully
// in-register RoPE, no LDS exchange. Column block bn maps to exactly one
// head: bn<16 q-head bn; 16..31 k-head; 32..47 v-head (v stored transposed
// to vtb[bh][d][t] via packed u16x4 stores: r-index = 4 consecutive t).
// ---------------------------------------------------------------------------
__global__ __launch_bounds__(256) void k_gemm_qkv(const u16* __restrict__ A,
                                                  const u16* __restrict__ B,
                                                  const float* __restrict__ cosb,
                                                  const float* __restrict__ sinb,
                                                  u16* __restrict__ qr,
                                                  u16* __restrict__ kr,
                                                  u16* __restrict__ vtb) {
  __shared__ __align__(16) u16 lA[128 * 64];
  __shared__ __align__(16) u16 lB[128 * 64];
  const int K = DMODEL;
  const int tid = threadIdx.x;
  const int wid = tid >> 6, lane = tid & 63;
  const int g = lane >> 4, q = lane & 15;
  const int wr = wid >> 1, wc = wid & 1;
  const int bn = blockIdx.x, bm = blockIdx.y;
  const int l8 = lane >> 3, l7 = lane & 7;
  const f32x4 fzero = {0.f, 0.f, 0.f, 0.f};
  f32x4 acc[4][4];
#pragma unroll
  for (int m = 0; m < 4; ++m)
#pragma unroll
    for (int n = 0; n < 4; ++n) acc[m][n] = fzero;

  const u16* Ab = A + (size_t)bm * 128 * K;
  const u16* Bb = B + (size_t)bn * 128 * K;

  for (int k0 = 0; k0 < K; k0 += 64) {
    __syncthreads();
#pragma unroll
    for (int i = 0; i < 4; ++i) {
      int chunk = wid * 4 + i;
      int row = chunk * 8 + l8;
      int scol = (l7 * 8) ^ ((row & 7) << 3);
      g2l16(Ab + (size_t)row * K + k0 + scol, lA + chunk * 512);
      g2l16(Bb + (size_t)row * K + k0 + scol, lB + chunk * 512);
    }
    __syncthreads();
#pragma unroll
    for (int kk = 0; kk < 2; ++kk) {
      bf16x8 af[4], bfr[4];
#pragma unroll
      for (int m = 0; m < 4; ++m) {
        int row = wr * 64 + m * 16 + q;
        int col = (kk * 32 + g * 8) ^ ((row & 7) << 3);
        af[m] = *(const bf16x8*)(lA + row * 64 + col);
      }
#pragma unroll
      for (int n = 0; n < 4; ++n) {
        int row = wc * 32 + (n & 1) * 16 + (n >> 1) * 64 + q;  // paired-col mapping
        int col = (kk * 32 + g * 8) ^ ((row & 7) << 3);
        bfr[n] = *(const bf16x8*)(lB + row * 64 + col);
      }
#pragma unroll
      for (int m = 0; m < 4; ++m)
#pragma unroll
        for (int n = 0; n < 4; ++n)
          acc[m][n] = __builtin_amdgcn_mfma_f32_16x16x32_bf16(af[m], bfr[n], acc[m][n], 0, 0, 0);
    }
  }

  // ---- fused epilogue ----
  const int h = bn & 15;
  const int which = bn >> 4;                 // 0=q, 1=k, 2=v
  const int b = bm >> 4;
  const int bh = b * 16 + h;
  const int tb0 = (bm & 15) * 128 + wr * 64; // + m*16 + g*4 + r -> token idx
  const float qscale = 0.08838834764831845f;

  if (which == 2) {
    // V: store transposed to vtb[bh][d][t]; 4 consecutive t packed per store.
    u16* vdst = vtb + (size_t)bh * HD * T_SEQ;
#pragma unroll
    for (int m = 0; m < 4; ++m)
#pragma unroll
      for (int n = 0; n < 4; ++n) {
        int c = wc * 32 + (n & 1) * 16 + (n >> 1) * 64 + q;
        int t0 = tb0 + m * 16 + g * 4;
        u16x4 pk;
#pragma unroll
        for (int r = 0; r < 4; ++r) pk[r] = f2b(acc[m][n][r]);
        *(u16x4*)(vdst + (size_t)c * T_SEQ + t0) = pk;
      }
  } else {
    u16* dst = (which ? kr : qr) + (size_t)bh * T_SEQ * HD;
    const float sc = which ? 1.0f : qscale;
#pragma unroll
    for (int m = 0; m < 4; ++m)
#pragma unroll
      for (int n = 0; n < 2; ++n) {
        int dm = wc * 32 + n * 16 + q;      // d % 64
#pragma unroll
        for (int r = 0; r < 4; ++r) {
          int t = tb0 + m * 16 + g * 4 + r;
          float cv = cosb[t * 64 + dm];
          float sv = sinb[t * 64 + dm];
          float x0 = acc[m][n][r];          // d = dm (low half)
          float x1 = acc[m][n + 2][r];      // d = dm + 64 (high half)
          dst[(size_t)t * HD + dm] = f2b((x0 * cv - x1 * sv) * sc);
          dst[(size_t)t * HD + 64 + dm] = f2b((x1 * cv + x0 * sv) * sc);
        }
      }
  }
}

// m97-style 128x128 GEMM for the output projection (EPI=1: f32 out).
template <int EPI>
__global__ __launch_bounds__(256) void k_gemm_nt(const u16* __restrict__ A,
                                                 const u16* __restrict__ B,
                                                 void* __restrict__ Cv,
                                                 int M, int N, int K) {
  __shared__ __align__(16) u16 lA[128 * 64];
  __shared__ __align__(16) u16 lB[128 * 64];
  const int tid = threadIdx.x;
  const int wid = tid >> 6, lane = tid & 63;
  const int g = lane >> 4, q = lane & 15;
  const int wr = wid >> 1, wc = wid & 1;
  const int bn = blockIdx.x, bm = blockIdx.y;
  const int l8 = lane >> 3, l7 = lane & 7;
  const f32x4 fzero = {0.f, 0.f, 0.f, 0.f};
  f32x4 acc[4][4];
#pragma unroll
  for (int m = 0; m < 4; ++m)
#pragma unroll
    for (int n = 0; n < 4; ++n) acc[m][n] = fzero;

  const u16* Ab = A + (size_t)bm * 128 * K;
  const u16* Bb = B + (size_t)bn * 128 * K;

  for (int k0 = 0; k0 < K; k0 += 64) {
    __syncthreads();
#pragma unroll
    for (int i = 0; i < 4; ++i) {
      int chunk = wid * 4 + i;
      int row = chunk * 8 + l8;
      int scol = (l7 * 8) ^ ((row & 7) << 3);
      g2l16(Ab + (size_t)row * K + k0 + scol, lA + chunk * 512);
      g2l16(Bb + (size_t)row * K + k0 + scol, lB + chunk * 512);
    }
    __syncthreads();
#pragma unroll
    for (int kk = 0; kk < 2; ++kk) {
      bf16x8 af[4], bfr[4];
#pragma unroll
      for (int m = 0; m < 4; ++m) {
        int row = wr * 64 + m * 16 + q;
        int col = (kk * 32 + g * 8) ^ ((row & 7) << 3);
        af[m] = *(const bf16x8*)(lA + row * 64 + col);
      }
#pragma unroll
      for (int n = 0; n < 4; ++n) {
        int row = wc * 64 + n * 16 + q;
        int col = (kk * 32 + g * 8) ^ ((row & 7) << 3);
        bfr[n] = *(const bf16x8*)(lB + row * 64 + col);
      }
#pragma unroll
      for (int m = 0; m < 4; ++m)
#pragma unroll
        for (int n = 0; n < 4; ++n)
          acc[m][n] = __builtin_amdgcn_mfma_f32_16x16x32_bf16(af[m], bfr[n], acc[m][n], 0, 0, 0);
    }
  }
  const int rbase = bm * 128 + wr * 64;
  const int cbase = bn * 128 + wc * 64;
#pragma unroll
  for (int m = 0; m < 4; ++m)
#pragma unroll
    for (int n = 0; n < 4; ++n) {
      int col = cbase + n * 16 + q;
#pragma unroll
      for (int r = 0; r < 4; ++r) {
        int row = rbase + m * 16 + g * 4 + r;
        if (EPI == 0)
          ((u16*)Cv)[(size_t)row * N + col] = f2b(acc[m][n][r]);
        else
          ((float*)Cv)[(size_t)row * N + col] = acc[m][n][r];
      }
    }
}

// Flash attention: grid (B*H, T/64). 4 waves/block, each wave owns 16 q-rows.
// Long q-tiles launch first (reverse qt) to smooth the causal tail.
__global__ __launch_bounds__(256) void k_attn(const u16* __restrict__ qr,
                                              const u16* __restrict__ kr,
                                              const u16* __restrict__ vtb,
                                              u16* __restrict__ ao) {
  __shared__ __align__(16) u16 lK[64 * 128];
  __shared__ __align__(16) u16 lV[128 * 64];
  __shared__ __align__(16) u16 lP[4][16 * 72];
  const int bh = blockIdx.x, b = bh >> 4, h = bh & 15;
  const int qt = (T_SEQ / 64 - 1) - blockIdx.y;
  const int tid = threadIdx.x;
  const int wid = tid >> 6, lane = tid & 63;
  const int g = lane >> 4, q = lane & 15;
  const int qw0 = qt * 64 + wid * 16;
  const u16* qb = qr + (size_t)bh * T_SEQ * HD;
  const u16* kbp = kr + (size_t)bh * T_SEQ * HD;
  const u16* vb = vtb + (size_t)bh * HD * T_SEQ;
  const f32x4 fzero = {0.f, 0.f, 0.f, 0.f};

  bf16x8 qf[4];
#pragma unroll
  for (int ks = 0; ks < 4; ++ks)
    qf[ks] = *(const bf16x8*)(qb + (size_t)(qw0 + q) * HD + ks * 32 + g * 8);

  f32x4 o_acc[8];
#pragma unroll
  for (int n = 0; n < 8; ++n) o_acc[n] = fzero;
  float m_run = -1e30f, l_run = 0.f;

  const int ntiles = qt + 1;
  for (int kt = 0; kt < ntiles; ++kt) {
    const int kb = kt * 64;
    __syncthreads();
#pragma unroll
    for (int i = 0; i < 4; ++i) {
      int chunk = wid * 4 + i;
      int row = chunk * 4 + g;
      int scol = (q * 8) ^ ((row & 7) << 3);
      g2l16(kbp + (size_t)(kb + row) * HD + scol, lK + chunk * 512);
    }
#pragma unroll
    for (int i = 0; i < 4; ++i) {
      int chunk = wid * 4 + i;
      int row = chunk * 8 + (lane >> 3);
      int scol = ((lane & 7) * 8) ^ ((row & 7) << 3);
      g2l16(vb + (size_t)row * T_SEQ + kb + scol, lV + chunk * 512);
    }
    __syncthreads();
    {
      f32x4 st[4];
#pragma unroll
      for (int m = 0; m < 4; ++m) st[m] = fzero;
#pragma unroll
      for (int ks = 0; ks < 4; ++ks) {
#pragma unroll
        for (int m = 0; m < 4; ++m) {
          int row = m * 16 + q;
          int col = (ks * 32 + g * 8) ^ ((row & 7) << 3);
          bf16x8 kf = *(const bf16x8*)(lK + row * 128 + col);
          st[m] = __builtin_amdgcn_mfma_f32_16x16x32_bf16(kf, qf[ks], st[m], 0, 0, 0);
        }
      }
      const int qrow = qw0 + q;
      float p[4][4];
      float pmax = -1e30f;
#pragma unroll
      for (int m = 0; m < 4; ++m)
#pragma unroll
        for (int r = 0; r < 4; ++r) {
          int kcol = kb + m * 16 + g * 4 + r;
          float s = (kcol <= qrow) ? st[m][r] : -1e30f;
          p[m][r] = s;
          pmax = fmaxf(pmax, s);
        }
      pmax = fmaxf(pmax, __shfl_xor(pmax, 16));
      pmax = fmaxf(pmax, __shfl_xor(pmax, 32));
      float m_new = fmaxf(m_run, pmax);
      float corr = __expf(m_run - m_new);
      float ls = 0.f;
#pragma unroll
      for (int m = 0; m < 4; ++m)
#pragma unroll
        for (int r = 0; r < 4; ++r) {
          float e = __expf(p[m][r] - m_new);
          p[m][r] = e;
          ls += e;
        }
      ls += __shfl_xor(ls, 16);
      ls += __shfl_xor(ls, 32);
      l_run = l_run * corr + ls;
      m_run = m_new;
#pragma unroll
      for (int m = 0; m < 4; ++m) {
#pragma unroll
        for (int rp = 0; rp < 2; ++rp) {
          u32 pk = (u32)f2b(p[m][rp * 2]) | ((u32)f2b(p[m][rp * 2 + 1]) << 16);
          *(u32*)(&lP[wid][q * 72 + m * 16 + g * 4 + rp * 2]) = pk;
        }
      }
      asm volatile("s_waitcnt lgkmcnt(0)" ::: "memory");
      __builtin_amdgcn_sched_barrier(0);
      float corr4[4];
#pragma unroll
      for (int r = 0; r < 4; ++r) corr4[r] = __shfl(corr, g * 4 + r);
#pragma unroll
      for (int n = 0; n < 8; ++n) {
#pragma unroll
        for (int r = 0; r < 4; ++r) o_acc[n][r] *= corr4[r];
      }
#pragma unroll
      for (int ks = 0; ks < 2; ++ks) {
        bf16x8 pf = *(const bf16x8*)(&lP[wid][q * 72 + ks * 32 + g * 8]);
#pragma unroll
        for (int n = 0; n < 8; ++n) {
          int row = n * 16 + q;
          int col = (ks * 32 + g * 8) ^ ((row & 7) << 3);
          bf16x8 vf = *(const bf16x8*)(lV + row * 64 + col);
          o_acc[n] = __builtin_amdgcn_mfma_f32_16x16x32_bf16(pf, vf, o_acc[n], 0, 0, 0);
        }
      }
    }
  }
  float linv[4];
#pragma unroll
  for (int r = 0; r < 4; ++r) {
    float lv = __shfl(l_run, g * 4 + r);
    linv[r] = 1.0f / lv;
  }
#pragma unroll
  for (int n = 0; n < 8; ++n)
#pragma unroll
    for (int r = 0; r < 4; ++r) {
      int trow = qw0 + g * 4 + r;
      ao[(size_t)(b * T_SEQ + trow) * DMODEL + h * HD + n * 16 + q] = f2b(o_acc[n][r] * linv[r]);
    }
}

extern "C" void kernel_launch(void* const* d_in, const int* in_sizes, int n_in,
                              void* d_out, int out_size, void* d_ws, size_t ws_size,
                              hipStream_t stream) {
  const float* x = (const float*)d_in[0];
  const float* w_qkv = (const float*)d_in[1];
  const float* w_out = (const float*)d_in[2];
  char* ws = (char*)d_ws;
  size_t off = 0;
  u16* xb = (u16*)(ws + off);    off += (size_t)MROWS * DMODEL * 2;   // also reused as ao
  u16* wqkvT = (u16*)(ws + off); off += (size_t)NQKV * DMODEL * 2;
  u16* woutT = (u16*)(ws + off); off += (size_t)DMODEL * DMODEL * 2;
  u16* qr = (u16*)(ws + off);    off += (size_t)32 * T_SEQ * HD * 2;
  u16* kr = (u16*)(ws + off);    off += (size_t)32 * T_SEQ * HD * 2;
  u16* vtb = (u16*)(ws + off);   off += (size_t)32 * T_SEQ * HD * 2;
  float* cosb = (float*)(ws + off); off += (size_t)T_SEQ * 64 * 4;
  float* sinb = (float*)(ws + off); off += (size_t)T_SEQ * 64 * 4;
  u16* ao = xb;

  k_f32_to_bf16<<<dim3(MROWS * DMODEL / (256 * 8)), 256, 0, stream>>>(x, xb, MROWS * DMODEL);
  k_transpose_bf16<<<dim3(NQKV / 32, DMODEL / 32), 256, 0, stream>>>(w_qkv, wqkvT, DMODEL, NQKV);
  k_transpose_bf16<<<dim3(DMODEL / 32, DMODEL / 32), 256, 0, stream>>>(w_out, woutT, DMODEL, DMODEL);
  k_rope_cache<<<dim3(T_SEQ * 64 / 256), 256, 0, stream>>>(cosb, sinb);
  k_gemm_qkv<<<dim3(NQKV / 128, MROWS / 128), 256, 0, stream>>>(xb, wqkvT, cosb, sinb, qr, kr, vtb);
  k_attn<<<dim3(32, T_SEQ / 64), 256, 0, stream>>>(qr, kr, vtb, ao);
  k_gemm_nt<1><<<dim3(DMODEL / 128, MROWS / 128), 256, 0, stream>>>(ao, woutT, d_out, MROWS, DMODEL, DMODEL);
}